// Round 1
// baseline (2834.103 us; speedup 1.0000x reference)
//
#include <hip/hip_runtime.h>

static constexpr int NN = 50000;    // nodes
static constexpr int NE = 1600000;  // edges
static constexpr int CH = 128;
static constexpr int NCLS = 40;
static constexpr size_t MAT_BYTES = (size_t)NN * CH * sizeof(float);  // 25.6 MB

// ---------------------------------------------------------------------------
// Y = X(N,128) @ W(128,128) + bias   [optional relu, optional deg-scaled bias]
// Block: 256 threads, 64 nodes/block. W cached in LDS (64 KB).
// Thread t handles (row = t/32 within 8-row pass, cols jb..jb+3 = (t%32)*4).
// ---------------------------------------------------------------------------
template<bool RELU, bool DEGBIAS>
__global__ __launch_bounds__(256, 2)
void gemm128(const float* __restrict__ X, const float* __restrict__ W,
             const float* __restrict__ b, const int* __restrict__ deg,
             float* __restrict__ Y, int n)
{
    __shared__ float Wl[128 * 128];   // 64 KB, row-major [k][j]
    __shared__ float fr[8][128];      // 8 input rows per pass
    __shared__ float bl[128];

    const int t = threadIdx.x;
    for (int i = t; i < (128 * 128) / 4; i += 256)
        reinterpret_cast<float4*>(Wl)[i] = reinterpret_cast<const float4*>(W)[i];
    if (t < 128) bl[t] = b[t];
    __syncthreads();

    const int nodeBase = blockIdx.x * 64;
    const int r  = t >> 5;         // 0..7: row within pass
    const int jb = (t & 31) * 4;   // output column base

    for (int p = 0; p < 8; ++p) {
        const int row0 = nodeBase + p * 8;
        // stage 8 input rows (each 32-thread group loads one row, float4 each)
        if (row0 + r < n)
            *reinterpret_cast<float4*>(&fr[r][jb]) =
                *reinterpret_cast<const float4*>(&X[(size_t)(row0 + r) * CH + jb]);
        __syncthreads();

        const int row = row0 + r;
        if (row < n) {
            float a0, a1, a2, a3;
            if (DEGBIAS) {
                const float dg = (float)deg[row];
                a0 = dg * bl[jb + 0]; a1 = dg * bl[jb + 1];
                a2 = dg * bl[jb + 2]; a3 = dg * bl[jb + 3];
            } else {
                a0 = bl[jb + 0]; a1 = bl[jb + 1];
                a2 = bl[jb + 2]; a3 = bl[jb + 3];
            }
            #pragma unroll 16
            for (int k = 0; k < 128; ++k) {
                const float f = fr[r][k];                               // LDS broadcast
                const float4 w4 = *reinterpret_cast<const float4*>(&Wl[k * 128 + jb]);
                a0 += f * w4.x; a1 += f * w4.y; a2 += f * w4.z; a3 += f * w4.w;
            }
            if (RELU) {
                a0 = fmaxf(a0, 0.f); a1 = fmaxf(a1, 0.f);
                a2 = fmaxf(a2, 0.f); a3 = fmaxf(a3, 0.f);
            }
            float4 o; o.x = a0; o.y = a1; o.z = a2; o.w = a3;
            *reinterpret_cast<float4*>(&Y[(size_t)row * CH + jb]) = o;
        }
        __syncthreads();
    }
}

// ---------------------------------------------------------------------------
// Y[src[e]] += X[dst[e]]  (128 floats per edge). One wave per edge, lane
// handles float2. Optionally counts deg[src].
// ---------------------------------------------------------------------------
template<bool COUNT>
__global__ __launch_bounds__(256)
void scatter_add(const int* __restrict__ src, const int* __restrict__ dst,
                 const float* __restrict__ X, float* __restrict__ Y,
                 int* __restrict__ deg)
{
    const int lane = threadIdx.x & 63;
    const int e = blockIdx.x * 4 + (threadIdx.x >> 6);
    const int s = src[e];
    const int d = dst[e];
    const float2 v = *reinterpret_cast<const float2*>(&X[(size_t)d * CH + lane * 2]);
    float* o = &Y[(size_t)s * CH + lane * 2];
    atomicAdd(o + 0, v.x);
    atomicAdd(o + 1, v.y);
    if (COUNT && lane == 0) atomicAdd(&deg[s], 1);
}

// ---------------------------------------------------------------------------
// out(N,40) = X(N,128) @ Wfc(128,40) + bfc. One thread per output element.
// ---------------------------------------------------------------------------
__global__ __launch_bounds__(256)
void fc_out(const float* __restrict__ X, const float* __restrict__ W,
            const float* __restrict__ b, float* __restrict__ Y)
{
    __shared__ float Wl[128 * NCLS];  // 20 KB
    __shared__ float bl[NCLS];
    const int t = threadIdx.x;
    for (int i = t; i < 128 * NCLS; i += 256) Wl[i] = W[i];
    if (t < NCLS) bl[t] = b[t];
    __syncthreads();

    const int idx = blockIdx.x * 256 + t;
    if (idx >= NN * NCLS) return;
    const int nrow = idx / NCLS;
    const int c    = idx % NCLS;
    const float* xr = &X[(size_t)nrow * CH];
    float acc = bl[c];
    #pragma unroll 8
    for (int k = 0; k < 128; ++k) acc += xr[k] * Wl[k * NCLS + c];
    Y[idx] = acc;
}

extern "C" void kernel_launch(void* const* d_in, const int* in_sizes, int n_in,
                              void* d_out, int out_size, void* d_ws, size_t ws_size,
                              hipStream_t stream) {
    const float* F   = (const float*)d_in[0];  // (1,N,128)
    const int*   EI  = (const int*)  d_in[1];  // (1,2,E) int32 (jax x64 disabled)
    // d_in[2] rank_mapping: unused (zeros)
    const float* W1  = (const float*)d_in[3];
    const float* b1  = (const float*)d_in[4];
    const float* W2  = (const float*)d_in[5];
    const float* b2  = (const float*)d_in[6];
    const float* Wfc = (const float*)d_in[7];
    const float* bfc = (const float*)d_in[8];
    float* out = (float*)d_out;

    char* ws = (char*)d_ws;
    float* A   = (float*)(ws);                  // H1, later T
    float* B   = (float*)(ws + MAT_BYTES);      // S1, later X2
    int*   deg = (int*)  (ws + 2 * MAT_BYTES);

    const int* src = EI;          // edge_index[0,:]
    const int* dst = EI + NE;     // edge_index[1,:]

    // zero accumulators
    hipMemsetAsync(B,   0, MAT_BYTES, stream);
    hipMemsetAsync(deg, 0, NN * sizeof(int), stream);

    // H1 = relu(F @ W1 + b1)  -> A
    gemm128<true, false><<<(NN + 63) / 64, 256, 0, stream>>>(F, W1, b1, nullptr, A, NN);

    // S1[s] += H1[d]  -> B   (+ deg count)
    scatter_add<true><<<NE / 4, 256, 0, stream>>>(src, dst, A, B, deg);

    // reuse A as T accumulator
    hipMemsetAsync(A, 0, MAT_BYTES, stream);

    // T[s] += S1[d]  -> A
    scatter_add<false><<<NE / 4, 256, 0, stream>>>(src, dst, B, A, nullptr);

    // X2 = T @ W2 + deg*b2  -> B
    gemm128<false, true><<<(NN + 63) / 64, 256, 0, stream>>>(A, W2, b2, deg, B, NN);

    // out = X2 @ Wfc + bfc
    fc_out<<<(NN * NCLS + 255) / 256, 256, 0, stream>>>(B, Wfc, bfc, out);
}

// Round 2
// 645.487 us; speedup vs baseline: 4.3906x; 4.3906x over previous
//
#include <hip/hip_runtime.h>

static constexpr int NN = 50000;    // nodes
static constexpr int NE = 1600000;  // edges
static constexpr int CH = 128;
static constexpr int NCLS = 40;
static constexpr size_t MAT_BYTES = (size_t)NN * CH * sizeof(float);  // 25.6 MB

// ---------------------------------------------------------------------------
// Y = X(N,128) @ W(128,128) + bias   [optional relu, optional deg-scaled bias]
// ---------------------------------------------------------------------------
template<bool RELU, bool DEGBIAS>
__global__ __launch_bounds__(256, 2)
void gemm128(const float* __restrict__ X, const float* __restrict__ W,
             const float* __restrict__ b, const int* __restrict__ deg,
             float* __restrict__ Y, int n)
{
    __shared__ float Wl[128 * 128];   // 64 KB, row-major [k][j]
    __shared__ float fr[8][128];      // 8 input rows per pass
    __shared__ float bl[128];

    const int t = threadIdx.x;
    for (int i = t; i < (128 * 128) / 4; i += 256)
        reinterpret_cast<float4*>(Wl)[i] = reinterpret_cast<const float4*>(W)[i];
    if (t < 128) bl[t] = b[t];
    __syncthreads();

    const int nodeBase = blockIdx.x * 64;
    const int r  = t >> 5;         // 0..7: row within pass
    const int jb = (t & 31) * 4;   // output column base

    for (int p = 0; p < 8; ++p) {
        const int row0 = nodeBase + p * 8;
        if (row0 + r < n)
            *reinterpret_cast<float4*>(&fr[r][jb]) =
                *reinterpret_cast<const float4*>(&X[(size_t)(row0 + r) * CH + jb]);
        __syncthreads();

        const int row = row0 + r;
        if (row < n) {
            float a0, a1, a2, a3;
            if (DEGBIAS) {
                const float dg = (float)deg[row];
                a0 = dg * bl[jb + 0]; a1 = dg * bl[jb + 1];
                a2 = dg * bl[jb + 2]; a3 = dg * bl[jb + 3];
            } else {
                a0 = bl[jb + 0]; a1 = bl[jb + 1];
                a2 = bl[jb + 2]; a3 = bl[jb + 3];
            }
            #pragma unroll 16
            for (int k = 0; k < 128; ++k) {
                const float f = fr[r][k];
                const float4 w4 = *reinterpret_cast<const float4*>(&Wl[k * 128 + jb]);
                a0 += f * w4.x; a1 += f * w4.y; a2 += f * w4.z; a3 += f * w4.w;
            }
            if (RELU) {
                a0 = fmaxf(a0, 0.f); a1 = fmaxf(a1, 0.f);
                a2 = fmaxf(a2, 0.f); a3 = fmaxf(a3, 0.f);
            }
            float4 o; o.x = a0; o.y = a1; o.z = a2; o.w = a3;
            *reinterpret_cast<float4*>(&Y[(size_t)row * CH + jb]) = o;
        }
        __syncthreads();
    }
}

// ---------------------------------------------------------------------------
// CSR build: deg count, exclusive scan, fill
// ---------------------------------------------------------------------------
__global__ __launch_bounds__(256)
void deg_count(const int* __restrict__ src, int* __restrict__ deg)
{
    const int e = blockIdx.x * 256 + threadIdx.x;
    if (e < NE) atomicAdd(&deg[src[e]], 1);
}

__global__ __launch_bounds__(1024)
void exscan(const int* __restrict__ deg, int* __restrict__ offs)
{
    __shared__ int buf[1024];
    __shared__ int carry;
    const int t = threadIdx.x;
    if (t == 0) carry = 0;
    __syncthreads();
    for (int base = 0; base < NN; base += 1024) {
        const int v = (base + t < NN) ? deg[base + t] : 0;
        buf[t] = v;
        __syncthreads();
        // Hillis-Steele inclusive scan
        for (int off = 1; off < 1024; off <<= 1) {
            const int x = (t >= off) ? buf[t - off] : 0;
            __syncthreads();
            buf[t] += x;
            __syncthreads();
        }
        const int total = buf[1023];
        if (base + t < NN) offs[base + t] = carry + buf[t] - v;  // exclusive
        __syncthreads();
        if (t == 0) carry += total;
        __syncthreads();
    }
    if (t == 0) offs[NN] = carry;
}

__global__ __launch_bounds__(256)
void csr_fill(const int* __restrict__ src, const int* __restrict__ dst,
              int* __restrict__ cursor, int* __restrict__ adj)
{
    const int e = blockIdx.x * 256 + threadIdx.x;
    if (e >= NE) return;
    const int pos = atomicAdd(&cursor[src[e]], 1);
    adj[pos] = dst[e];
}

// ---------------------------------------------------------------------------
// Y[s] = sum_{i in [offs[s],offs[s+1])} X[adj[i]]  — one wave per node,
// lane holds 2 floats in registers. No atomics; each output written once.
// ---------------------------------------------------------------------------
__global__ __launch_bounds__(256)
void gather_sum(const int* __restrict__ offs, const int* __restrict__ adj,
                const float* __restrict__ X, float* __restrict__ Y)
{
    const int lane = threadIdx.x & 63;
    const int s = blockIdx.x * 4 + (threadIdx.x >> 6);
    if (s >= NN) return;
    const int beg = offs[s];
    const int end = offs[s + 1];
    const int c = lane * 2;
    float a0 = 0.f, a1 = 0.f;
    int i = beg;
    for (; i + 4 <= end; i += 4) {
        const int d0 = adj[i], d1 = adj[i + 1], d2 = adj[i + 2], d3 = adj[i + 3];
        const float2 v0 = *reinterpret_cast<const float2*>(&X[(size_t)d0 * CH + c]);
        const float2 v1 = *reinterpret_cast<const float2*>(&X[(size_t)d1 * CH + c]);
        const float2 v2 = *reinterpret_cast<const float2*>(&X[(size_t)d2 * CH + c]);
        const float2 v3 = *reinterpret_cast<const float2*>(&X[(size_t)d3 * CH + c]);
        a0 += v0.x + v1.x + v2.x + v3.x;
        a1 += v0.y + v1.y + v2.y + v3.y;
    }
    for (; i < end; ++i) {
        const int d = adj[i];
        const float2 v = *reinterpret_cast<const float2*>(&X[(size_t)d * CH + c]);
        a0 += v.x; a1 += v.y;
    }
    float2 o; o.x = a0; o.y = a1;
    *reinterpret_cast<float2*>(&Y[(size_t)s * CH + c]) = o;
}

// ---------------------------------------------------------------------------
// out(N,40) = X(N,128) @ Wfc(128,40) + bfc
// ---------------------------------------------------------------------------
__global__ __launch_bounds__(256)
void fc_out(const float* __restrict__ X, const float* __restrict__ W,
            const float* __restrict__ b, float* __restrict__ Y)
{
    __shared__ float Wl[128 * NCLS];  // 20 KB
    __shared__ float bl[NCLS];
    const int t = threadIdx.x;
    for (int i = t; i < 128 * NCLS; i += 256) Wl[i] = W[i];
    if (t < NCLS) bl[t] = b[t];
    __syncthreads();

    const int idx = blockIdx.x * 256 + t;
    if (idx >= NN * NCLS) return;
    const int nrow = idx / NCLS;
    const int c    = idx % NCLS;
    const float* xr = &X[(size_t)nrow * CH];
    float acc = bl[c];
    #pragma unroll 8
    for (int k = 0; k < 128; ++k) acc += xr[k] * Wl[k * NCLS + c];
    Y[idx] = acc;
}

extern "C" void kernel_launch(void* const* d_in, const int* in_sizes, int n_in,
                              void* d_out, int out_size, void* d_ws, size_t ws_size,
                              hipStream_t stream) {
    const float* F   = (const float*)d_in[0];  // (1,N,128)
    const int*   EI  = (const int*)  d_in[1];  // (1,2,E) int32
    const float* W1  = (const float*)d_in[3];
    const float* b1  = (const float*)d_in[4];
    const float* W2  = (const float*)d_in[5];
    const float* b2  = (const float*)d_in[6];
    const float* Wfc = (const float*)d_in[7];
    const float* bfc = (const float*)d_in[8];
    float* out = (float*)d_out;

    char* ws = (char*)d_ws;
    float* A      = (float*)(ws);                                   // 25.6 MB
    float* B      = (float*)(ws + MAT_BYTES);                       // 25.6 MB
    int*   deg    = (int*)  (ws + 2 * MAT_BYTES);                   // 200 KB
    int*   offs   = deg    + NN;                                    // 200 KB (+4)
    int*   cursor = offs   + NN + 1;                                // 200 KB
    int*   adj    = cursor + NN;                                    // 6.4 MB

    const int* src = EI;          // edge_index[0,:]
    const int* dst = EI + NE;     // edge_index[1,:]

    // ---- CSR build (src-keyed) ----
    hipMemsetAsync(deg, 0, NN * sizeof(int), stream);
    deg_count<<<(NE + 255) / 256, 256, 0, stream>>>(src, deg);
    exscan<<<1, 1024, 0, stream>>>(deg, offs);
    hipMemcpyAsync(cursor, offs, NN * sizeof(int), hipMemcpyDeviceToDevice, stream);
    csr_fill<<<(NE + 255) / 256, 256, 0, stream>>>(src, dst, cursor, adj);

    // ---- H1 = relu(F @ W1 + b1) -> A ----
    gemm128<true, false><<<(NN + 63) / 64, 256, 0, stream>>>(F, W1, b1, nullptr, A, NN);

    // ---- S1[s] = sum H1[dst] -> B ----
    gather_sum<<<(NN + 3) / 4, 256, 0, stream>>>(offs, adj, A, B);

    // ---- T[s] = sum S1[dst] -> A ----
    gather_sum<<<(NN + 3) / 4, 256, 0, stream>>>(offs, adj, B, A);

    // ---- X2 = T @ W2 + deg*b2 -> B ----
    gemm128<false, true><<<(NN + 63) / 64, 256, 0, stream>>>(A, W2, b2, deg, B, NN);

    // ---- out = X2 @ Wfc + bfc ----
    fc_out<<<(NN * NCLS + 255) / 256, 256, 0, stream>>>(B, Wfc, bfc, out);
}

// Round 3
// 558.272 us; speedup vs baseline: 5.0766x; 1.1562x over previous
//
#include <hip/hip_runtime.h>

static constexpr int NN = 50000;    // nodes
static constexpr int NE = 1600000;  // edges
static constexpr int CH = 128;
static constexpr int NCLS = 40;
static constexpr size_t MAT_BYTES = (size_t)NN * CH * sizeof(float);  // 25.6 MB
static constexpr int SCAN_B = 256;
static constexpr int NBLK = (NN + SCAN_B - 1) / SCAN_B;  // 196

// ---------------------------------------------------------------------------
// Y = X(N,128) @ W(128,128) + bias   [optional relu, optional deg-scaled bias]
// ---------------------------------------------------------------------------
template<bool RELU, bool DEGBIAS>
__global__ __launch_bounds__(256, 2)
void gemm128(const float* __restrict__ X, const float* __restrict__ W,
             const float* __restrict__ b, const int* __restrict__ deg,
             float* __restrict__ Y, int n)
{
    __shared__ float Wl[128 * 128];   // 64 KB, row-major [k][j]
    __shared__ float fr[8][128];      // 8 input rows per pass
    __shared__ float bl[128];

    const int t = threadIdx.x;
    for (int i = t; i < (128 * 128) / 4; i += 256)
        reinterpret_cast<float4*>(Wl)[i] = reinterpret_cast<const float4*>(W)[i];
    if (t < 128) bl[t] = b[t];
    __syncthreads();

    const int nodeBase = blockIdx.x * 64;
    const int r  = t >> 5;         // 0..7: row within pass
    const int jb = (t & 31) * 4;   // output column base

    for (int p = 0; p < 8; ++p) {
        const int row0 = nodeBase + p * 8;
        if (row0 + r < n)
            *reinterpret_cast<float4*>(&fr[r][jb]) =
                *reinterpret_cast<const float4*>(&X[(size_t)(row0 + r) * CH + jb]);
        __syncthreads();

        const int row = row0 + r;
        if (row < n) {
            float a0, a1, a2, a3;
            if (DEGBIAS) {
                const float dg = (float)deg[row];
                a0 = dg * bl[jb + 0]; a1 = dg * bl[jb + 1];
                a2 = dg * bl[jb + 2]; a3 = dg * bl[jb + 3];
            } else {
                a0 = bl[jb + 0]; a1 = bl[jb + 1];
                a2 = bl[jb + 2]; a3 = bl[jb + 3];
            }
            #pragma unroll 16
            for (int k = 0; k < 128; ++k) {
                const float f = fr[r][k];
                const float4 w4 = *reinterpret_cast<const float4*>(&Wl[k * 128 + jb]);
                a0 += f * w4.x; a1 += f * w4.y; a2 += f * w4.z; a3 += f * w4.w;
            }
            if (RELU) {
                a0 = fmaxf(a0, 0.f); a1 = fmaxf(a1, 0.f);
                a2 = fmaxf(a2, 0.f); a3 = fmaxf(a3, 0.f);
            }
            float4 o; o.x = a0; o.y = a1; o.z = a2; o.w = a3;
            *reinterpret_cast<float4*>(&Y[(size_t)row * CH + jb]) = o;
        }
        __syncthreads();
    }
}

// ---------------------------------------------------------------------------
// CSR build: deg count (4 edges/thread), 2-level scan, fill (4 edges/thread)
// ---------------------------------------------------------------------------
__global__ __launch_bounds__(256)
void deg_count(const int* __restrict__ src, int* __restrict__ deg)
{
    const int e0 = blockIdx.x * 1024 + threadIdx.x;
    #pragma unroll
    for (int k = 0; k < 4; ++k) {
        const int e = e0 + k * 256;
        if (e < NE) atomicAdd(&deg[src[e]], 1);
    }
}

// local exclusive scan per 256-block + block sums
__global__ __launch_bounds__(SCAN_B)
void scan_local(const int* __restrict__ deg, int* __restrict__ local,
                int* __restrict__ bsum)
{
    __shared__ int buf[SCAN_B];
    const int t = threadIdx.x;
    const int g = blockIdx.x * SCAN_B + t;
    const int v = (g < NN) ? deg[g] : 0;
    buf[t] = v;
    __syncthreads();
    #pragma unroll
    for (int off = 1; off < SCAN_B; off <<= 1) {
        const int x = (t >= off) ? buf[t - off] : 0;
        __syncthreads();
        buf[t] += x;
        __syncthreads();
    }
    if (g < NN) local[g] = buf[t] - v;          // exclusive within block
    if (t == SCAN_B - 1) bsum[blockIdx.x] = buf[t];
}

// scan the 196 block sums (one block); bsum becomes exclusive bases, bsum[NBLK]=total
__global__ __launch_bounds__(SCAN_B)
void scan_bsums(int* __restrict__ bsum)
{
    __shared__ int buf[SCAN_B];
    const int t = threadIdx.x;
    const int v = (t < NBLK) ? bsum[t] : 0;
    buf[t] = v;
    __syncthreads();
    #pragma unroll
    for (int off = 1; off < SCAN_B; off <<= 1) {
        const int x = (t >= off) ? buf[t - off] : 0;
        __syncthreads();
        buf[t] += x;
        __syncthreads();
    }
    if (t < NBLK) bsum[t] = buf[t] - v;         // exclusive base per block
    if (t == SCAN_B - 1) bsum[NBLK] = buf[t];   // grand total (== NE)
}

__global__ __launch_bounds__(SCAN_B)
void scan_add(const int* __restrict__ local, const int* __restrict__ bsum,
              int* __restrict__ offs, int* __restrict__ cursor)
{
    const int g = blockIdx.x * SCAN_B + threadIdx.x;
    if (g < NN) {
        const int o = local[g] + bsum[blockIdx.x];
        offs[g] = o;
        cursor[g] = o;
    }
    if (g == 0) offs[NN] = bsum[NBLK];
}

__global__ __launch_bounds__(256)
void csr_fill(const int* __restrict__ src, const int* __restrict__ dst,
              int* __restrict__ cursor, int* __restrict__ adj)
{
    const int e0 = blockIdx.x * 1024 + threadIdx.x;
    #pragma unroll
    for (int k = 0; k < 4; ++k) {
        const int e = e0 + k * 256;
        if (e < NE) {
            const int pos = atomicAdd(&cursor[src[e]], 1);
            adj[pos] = dst[e];
        }
    }
}

// ---------------------------------------------------------------------------
// Y[s] = sum_{i in [offs[s],offs[s+1])} X[adj[i]]  — one wave per node
// ---------------------------------------------------------------------------
__global__ __launch_bounds__(256)
void gather_sum(const int* __restrict__ offs, const int* __restrict__ adj,
                const float* __restrict__ X, float* __restrict__ Y)
{
    const int lane = threadIdx.x & 63;
    const int s = blockIdx.x * 4 + (threadIdx.x >> 6);
    if (s >= NN) return;
    const int beg = offs[s];
    const int end = offs[s + 1];
    const int c = lane * 2;
    float a0 = 0.f, a1 = 0.f;
    int i = beg;
    for (; i + 4 <= end; i += 4) {
        const int d0 = adj[i], d1 = adj[i + 1], d2 = adj[i + 2], d3 = adj[i + 3];
        const float2 v0 = *reinterpret_cast<const float2*>(&X[(size_t)d0 * CH + c]);
        const float2 v1 = *reinterpret_cast<const float2*>(&X[(size_t)d1 * CH + c]);
        const float2 v2 = *reinterpret_cast<const float2*>(&X[(size_t)d2 * CH + c]);
        const float2 v3 = *reinterpret_cast<const float2*>(&X[(size_t)d3 * CH + c]);
        a0 += v0.x + v1.x + v2.x + v3.x;
        a1 += v0.y + v1.y + v2.y + v3.y;
    }
    for (; i < end; ++i) {
        const int d = adj[i];
        const float2 v = *reinterpret_cast<const float2*>(&X[(size_t)d * CH + c]);
        a0 += v.x; a1 += v.y;
    }
    float2 o; o.x = a0; o.y = a1;
    *reinterpret_cast<float2*>(&Y[(size_t)s * CH + c]) = o;
}

// ---------------------------------------------------------------------------
// out(N,40) = X(N,128) @ Wfc(128,40) + bfc
// ---------------------------------------------------------------------------
__global__ __launch_bounds__(256)
void fc_out(const float* __restrict__ X, const float* __restrict__ W,
            const float* __restrict__ b, float* __restrict__ Y)
{
    __shared__ float Wl[128 * NCLS];  // 20 KB
    __shared__ float bl[NCLS];
    const int t = threadIdx.x;
    for (int i = t; i < 128 * NCLS; i += 256) Wl[i] = W[i];
    if (t < NCLS) bl[t] = b[t];
    __syncthreads();

    const int idx = blockIdx.x * 256 + t;
    if (idx >= NN * NCLS) return;
    const int nrow = idx / NCLS;
    const int c    = idx % NCLS;
    const float* xr = &X[(size_t)nrow * CH];
    float acc = bl[c];
    #pragma unroll 8
    for (int k = 0; k < 128; ++k) acc += xr[k] * Wl[k * NCLS + c];
    Y[idx] = acc;
}

extern "C" void kernel_launch(void* const* d_in, const int* in_sizes, int n_in,
                              void* d_out, int out_size, void* d_ws, size_t ws_size,
                              hipStream_t stream) {
    const float* F   = (const float*)d_in[0];  // (1,N,128)
    const int*   EI  = (const int*)  d_in[1];  // (1,2,E) int32
    const float* W1  = (const float*)d_in[3];
    const float* b1  = (const float*)d_in[4];
    const float* W2  = (const float*)d_in[5];
    const float* b2  = (const float*)d_in[6];
    const float* Wfc = (const float*)d_in[7];
    const float* bfc = (const float*)d_in[8];
    float* out = (float*)d_out;

    char* ws = (char*)d_ws;
    float* A      = (float*)(ws);                                   // 25.6 MB
    float* B      = (float*)(ws + MAT_BYTES);                       // 25.6 MB
    int*   deg    = (int*)  (ws + 2 * MAT_BYTES);                   // NN
    int*   offs   = deg    + NN;                                    // NN+1
    int*   cursor = offs   + NN + 1;                                // NN
    int*   local  = cursor + NN;                                    // NN
    int*   bsum   = local  + NN;                                    // NBLK+1
    int*   adj    = bsum   + NBLK + 1;                              // NE (6.4 MB)

    const int* src = EI;          // edge_index[0,:]
    const int* dst = EI + NE;     // edge_index[1,:]

    // ---- CSR build (src-keyed) ----
    hipMemsetAsync(deg, 0, NN * sizeof(int), stream);
    deg_count<<<(NE + 1023) / 1024, 256, 0, stream>>>(src, deg);
    scan_local<<<NBLK, SCAN_B, 0, stream>>>(deg, local, bsum);
    scan_bsums<<<1, SCAN_B, 0, stream>>>(bsum);
    scan_add<<<NBLK, SCAN_B, 0, stream>>>(local, bsum, offs, cursor);
    csr_fill<<<(NE + 1023) / 1024, 256, 0, stream>>>(src, dst, cursor, adj);

    // ---- H1 = relu(F @ W1 + b1) -> A ----
    gemm128<true, false><<<(NN + 63) / 64, 256, 0, stream>>>(F, W1, b1, nullptr, A, NN);

    // ---- S1[s] = sum H1[dst] -> B ----
    gather_sum<<<(NN + 3) / 4, 256, 0, stream>>>(offs, adj, A, B);

    // ---- T[s] = sum S1[dst] -> A ----
    gather_sum<<<(NN + 3) / 4, 256, 0, stream>>>(offs, adj, B, A);

    // ---- X2 = T @ W2 + deg*b2 -> B ----
    gemm128<false, true><<<(NN + 63) / 64, 256, 0, stream>>>(A, W2, b2, deg, B, NN);

    // ---- out = X2 @ Wfc + bfc ----
    fc_out<<<(NN * NCLS + 255) / 256, 256, 0, stream>>>(B, Wfc, bfc, out);
}

// Round 4
// 413.178 us; speedup vs baseline: 6.8593x; 1.3512x over previous
//
#include <hip/hip_runtime.h>

static constexpr int NN = 50000;    // nodes
static constexpr int NE = 1600000;  // edges
static constexpr int CH = 128;
static constexpr int NCLS = 40;
static constexpr size_t MAT_BYTES = (size_t)NN * CH * sizeof(float);  // 25.6 MB

static constexpr int NPB  = 64;                        // nodes per bucket
static constexpr int NBUK = (NN + NPB - 1) / NPB;      // 782
static constexpr int EPB  = 8192;                      // edges per hist block
static constexpr int NHB  = (NE + EPB - 1) / EPB;      // 196
static constexpr int NS   = NBUK * NHB;                // 153272 hist entries
static constexpr int SCAN_B = 256;
static constexpr int NSB  = (NS + SCAN_B - 1) / SCAN_B; // 599 (<=1024)
static constexpr int CAP  = 4096;                      // LDS edges per chunk

// ---------------------------------------------------------------------------
// Y = X(N,128) @ W(128,128) + bias   [optional relu, optional deg-scaled bias]
// ---------------------------------------------------------------------------
template<bool RELU, bool DEGBIAS>
__global__ __launch_bounds__(256, 2)
void gemm128(const float* __restrict__ X, const float* __restrict__ W,
             const float* __restrict__ b, const int* __restrict__ deg,
             float* __restrict__ Y, int n)
{
    __shared__ float Wl[128 * 128];   // 64 KB, row-major [k][j]
    __shared__ float fr[8][128];
    __shared__ float bl[128];

    const int t = threadIdx.x;
    for (int i = t; i < (128 * 128) / 4; i += 256)
        reinterpret_cast<float4*>(Wl)[i] = reinterpret_cast<const float4*>(W)[i];
    if (t < 128) bl[t] = b[t];
    __syncthreads();

    const int nodeBase = blockIdx.x * 64;
    const int r  = t >> 5;
    const int jb = (t & 31) * 4;

    for (int p = 0; p < 8; ++p) {
        const int row0 = nodeBase + p * 8;
        if (row0 + r < n)
            *reinterpret_cast<float4*>(&fr[r][jb]) =
                *reinterpret_cast<const float4*>(&X[(size_t)(row0 + r) * CH + jb]);
        __syncthreads();

        const int row = row0 + r;
        if (row < n) {
            float a0, a1, a2, a3;
            if (DEGBIAS) {
                const float dg = (float)deg[row];
                a0 = dg * bl[jb + 0]; a1 = dg * bl[jb + 1];
                a2 = dg * bl[jb + 2]; a3 = dg * bl[jb + 3];
            } else {
                a0 = bl[jb + 0]; a1 = bl[jb + 1];
                a2 = bl[jb + 2]; a3 = bl[jb + 3];
            }
            #pragma unroll 16
            for (int k = 0; k < 128; ++k) {
                const float f = fr[r][k];
                const float4 w4 = *reinterpret_cast<const float4*>(&Wl[k * 128 + jb]);
                a0 += f * w4.x; a1 += f * w4.y; a2 += f * w4.z; a3 += f * w4.w;
            }
            if (RELU) {
                a0 = fmaxf(a0, 0.f); a1 = fmaxf(a1, 0.f);
                a2 = fmaxf(a2, 0.f); a3 = fmaxf(a3, 0.f);
            }
            float4 o; o.x = a0; o.y = a1; o.z = a2; o.w = a3;
            *reinterpret_cast<float4*>(&Y[(size_t)row * CH + jb]) = o;
        }
        __syncthreads();
    }
}

// ---------------------------------------------------------------------------
// Bucketing: per-block LDS histogram over 782 coarse buckets (src>>6)
// ---------------------------------------------------------------------------
__global__ __launch_bounds__(256)
void bucket_hist(const int* __restrict__ src, int* __restrict__ H)
{
    __shared__ int h[NBUK];
    const int t = threadIdx.x;
    for (int i = t; i < NBUK; i += 256) h[i] = 0;
    __syncthreads();
    const int e0 = blockIdx.x * EPB;
    for (int i = t; i < EPB; i += 256) {
        const int e = e0 + i;
        if (e < NE) atomicAdd(&h[src[e] >> 6], 1);
    }
    __syncthreads();
    for (int i = t; i < NBUK; i += 256) H[i * NHB + blockIdx.x] = h[i];
}

// exclusive scan of H (NS entries), two-level, in place
__global__ __launch_bounds__(SCAN_B)
void scan_local(int* __restrict__ H, int* __restrict__ bsum)
{
    __shared__ int buf[SCAN_B];
    const int t = threadIdx.x;
    const int g = blockIdx.x * SCAN_B + t;
    const int v = (g < NS) ? H[g] : 0;
    buf[t] = v;
    __syncthreads();
    #pragma unroll
    for (int off = 1; off < SCAN_B; off <<= 1) {
        const int x = (t >= off) ? buf[t - off] : 0;
        __syncthreads();
        buf[t] += x;
        __syncthreads();
    }
    if (g < NS) H[g] = buf[t] - v;              // exclusive within block
    if (t == SCAN_B - 1) bsum[blockIdx.x] = buf[t];
}

__global__ __launch_bounds__(1024)
void scan_bsums(int* __restrict__ bsum)
{
    __shared__ int buf[1024];
    const int t = threadIdx.x;
    const int v = (t < NSB) ? bsum[t] : 0;
    buf[t] = v;
    __syncthreads();
    #pragma unroll
    for (int off = 1; off < 1024; off <<= 1) {
        const int x = (t >= off) ? buf[t - off] : 0;
        __syncthreads();
        buf[t] += x;
        __syncthreads();
    }
    if (t < NSB) bsum[t] = buf[t] - v;
    if (t == 1023) bsum[NSB] = buf[t];
}

__global__ __launch_bounds__(SCAN_B)
void scan_add(int* __restrict__ H, const int* __restrict__ bsum)
{
    const int g = blockIdx.x * SCAN_B + threadIdx.x;
    if (g < NS) H[g] += bsum[blockIdx.x];
}

// scatter packed edges ((src&63)<<16 | dst) into bucket-grouped EP
__global__ __launch_bounds__(256)
void bucket_scatter(const int* __restrict__ src, const int* __restrict__ dst,
                    const int* __restrict__ S, int* __restrict__ EP)
{
    __shared__ int cur[NBUK];
    const int t = threadIdx.x;
    for (int i = t; i < NBUK; i += 256) cur[i] = S[i * NHB + blockIdx.x];
    __syncthreads();
    const int e0 = blockIdx.x * EPB;
    for (int i = t; i < EPB; i += 256) {
        const int e = e0 + i;
        if (e < NE) {
            const int s = src[e];
            const int pos = atomicAdd(&cur[s >> 6], 1);
            EP[pos] = ((s & 63) << 16) | dst[e];
        }
    }
}

// ---------------------------------------------------------------------------
// Fused gather: one block per bucket. LDS counting-sort by local node, then
// wave w accumulates nodes [w*16, w*16+16) in registers. No global atomics.
// ---------------------------------------------------------------------------
template<bool WRITE_DEG>
__global__ __launch_bounds__(256)
void bucket_gather(const int* __restrict__ S, const int* __restrict__ EP,
                   const float* __restrict__ X, float* __restrict__ Y,
                   int* __restrict__ deg)
{
    __shared__ int raw[CAP];                 // 16 KB
    __shared__ unsigned short srt[CAP];      // 8 KB
    __shared__ int hist[NPB], cur[NPB], segBeg[NPB + 1], degSum[NPB];

    const int t = threadIdx.x;
    const int w = t >> 6;
    const int lane = t & 63;
    const int b = blockIdx.x;
    const int node0 = b * NPB;
    const int nNodes = min(NPB, NN - node0);
    const int beg = S[b * NHB];
    const int end = (b == NBUK - 1) ? NE : S[(b + 1) * NHB];
    const int cbase = lane * 2;

    float2 acc[16];
    #pragma unroll
    for (int i = 0; i < 16; ++i) acc[i] = make_float2(0.f, 0.f);
    if (WRITE_DEG && t < NPB) degSum[t] = 0;

    for (int cbeg = beg; cbeg < end; cbeg += CAP) {
        const int C = min(CAP, end - cbeg);
        for (int i = t; i < C; i += 256) raw[i] = EP[cbeg + i];
        if (t < NPB) hist[t] = 0;
        __syncthreads();
        for (int i = t; i < C; i += 256) atomicAdd(&hist[raw[i] >> 16], 1);
        __syncthreads();
        if (t == 0) {
            int s = 0;
            for (int i = 0; i < NPB; ++i) { segBeg[i] = s; s += hist[i]; }
            segBeg[NPB] = s;
        }
        if (WRITE_DEG && t < NPB) degSum[t] += hist[t];
        __syncthreads();
        if (t < NPB) cur[t] = segBeg[t];
        __syncthreads();
        for (int i = t; i < C; i += 256) {
            const int p = raw[i];
            const int pos = atomicAdd(&cur[p >> 16], 1);
            srt[pos] = (unsigned short)(p & 0xFFFF);
        }
        __syncthreads();

        #pragma unroll
        for (int ni = 0; ni < 16; ++ni) {
            const int n = w * 16 + ni;
            if (n < nNodes) {
                const int sb = segBeg[n], se = segBeg[n + 1];
                float ax = acc[ni].x, ay = acc[ni].y;
                int i = sb;
                for (; i + 4 <= se; i += 4) {
                    const int d0 = srt[i], d1 = srt[i + 1], d2 = srt[i + 2], d3 = srt[i + 3];
                    const float2 v0 = *reinterpret_cast<const float2*>(&X[(size_t)d0 * CH + cbase]);
                    const float2 v1 = *reinterpret_cast<const float2*>(&X[(size_t)d1 * CH + cbase]);
                    const float2 v2 = *reinterpret_cast<const float2*>(&X[(size_t)d2 * CH + cbase]);
                    const float2 v3 = *reinterpret_cast<const float2*>(&X[(size_t)d3 * CH + cbase]);
                    ax += v0.x + v1.x + v2.x + v3.x;
                    ay += v0.y + v1.y + v2.y + v3.y;
                }
                for (; i < se; ++i) {
                    const int d = srt[i];
                    const float2 v = *reinterpret_cast<const float2*>(&X[(size_t)d * CH + cbase]);
                    ax += v.x; ay += v.y;
                }
                acc[ni].x = ax; acc[ni].y = ay;
            }
        }
        __syncthreads();
    }

    #pragma unroll
    for (int ni = 0; ni < 16; ++ni) {
        const int n = w * 16 + ni;
        if (n < nNodes)
            *reinterpret_cast<float2*>(&Y[(size_t)(node0 + n) * CH + cbase]) = acc[ni];
    }
    if (WRITE_DEG && t < nNodes) deg[node0 + t] = degSum[t];
}

// ---------------------------------------------------------------------------
// out(N,40) = X(N,128) @ Wfc(128,40) + bfc
// ---------------------------------------------------------------------------
__global__ __launch_bounds__(256)
void fc_out(const float* __restrict__ X, const float* __restrict__ W,
            const float* __restrict__ b, float* __restrict__ Y)
{
    __shared__ float Wl[128 * NCLS];  // 20 KB
    __shared__ float bl[NCLS];
    const int t = threadIdx.x;
    for (int i = t; i < 128 * NCLS; i += 256) Wl[i] = W[i];
    if (t < NCLS) bl[t] = b[t];
    __syncthreads();

    const int idx = blockIdx.x * 256 + t;
    if (idx >= NN * NCLS) return;
    const int nrow = idx / NCLS;
    const int c    = idx % NCLS;
    const float* xr = &X[(size_t)nrow * CH];
    float acc = bl[c];
    #pragma unroll 8
    for (int k = 0; k < 128; ++k) acc += xr[k] * Wl[k * NCLS + c];
    Y[idx] = acc;
}

extern "C" void kernel_launch(void* const* d_in, const int* in_sizes, int n_in,
                              void* d_out, int out_size, void* d_ws, size_t ws_size,
                              hipStream_t stream) {
    const float* F   = (const float*)d_in[0];  // (1,N,128)
    const int*   EI  = (const int*)  d_in[1];  // (1,2,E) int32
    const float* W1  = (const float*)d_in[3];
    const float* b1  = (const float*)d_in[4];
    const float* W2  = (const float*)d_in[5];
    const float* b2  = (const float*)d_in[6];
    const float* Wfc = (const float*)d_in[7];
    const float* bfc = (const float*)d_in[8];
    float* out = (float*)d_out;

    char* ws = (char*)d_ws;
    float* A    = (float*)(ws);                       // 25.6 MB
    float* B    = (float*)(ws + MAT_BYTES);           // 25.6 MB
    int*   EP   = (int*)  (ws + 2 * MAT_BYTES);       // NE ints (6.4 MB)
    int*   H    = EP   + NE;                          // NS ints (613 KB)
    int*   bsum = H    + NS;                          // NSB+1 ints
    int*   deg  = bsum + NSB + 1;                     // NN ints

    const int* src = EI;          // edge_index[0,:]
    const int* dst = EI + NE;     // edge_index[1,:]

    // ---- bucket edges by src>>6 (no global atomics, coalesced-ish writes) ----
    bucket_hist<<<NHB, 256, 0, stream>>>(src, H);
    scan_local<<<NSB, SCAN_B, 0, stream>>>(H, bsum);
    scan_bsums<<<1, 1024, 0, stream>>>(bsum);
    scan_add<<<NSB, SCAN_B, 0, stream>>>(H, bsum);
    bucket_scatter<<<NHB, 256, 0, stream>>>(src, dst, H, EP);

    // ---- H1 = relu(F @ W1 + b1) -> A ----
    gemm128<true, false><<<(NN + 63) / 64, 256, 0, stream>>>(F, W1, b1, nullptr, A, NN);

    // ---- S1[s] = sum H1[dst] -> B  (+ deg) ----
    bucket_gather<true><<<NBUK, 256, 0, stream>>>(H, EP, A, B, deg);

    // ---- U[s] = sum S1[dst] -> A ----
    bucket_gather<false><<<NBUK, 256, 0, stream>>>(H, EP, B, A, nullptr);

    // ---- X2 = U @ W2 + deg*b2 -> B ----
    gemm128<false, true><<<(NN + 63) / 64, 256, 0, stream>>>(A, W2, b2, deg, B, NN);

    // ---- out = X2 @ Wfc + bfc ----
    fc_out<<<(NN * NCLS + 255) / 256, 256, 0, stream>>>(B, Wfc, bfc, out);
}

// Round 5
// 323.988 us; speedup vs baseline: 8.7476x; 1.2753x over previous
//
#include <hip/hip_runtime.h>

static constexpr int NN = 50000;    // nodes
static constexpr int NE = 1600000;  // edges
static constexpr int CH = 128;
static constexpr int NCLS = 40;
static constexpr size_t BF_BYTES = (size_t)NN * CH * 2;   // 12.8 MB bf16 matrix

static constexpr int NPB  = 64;                        // nodes per bucket
static constexpr int NBUK = (NN + NPB - 1) / NPB;      // 782
static constexpr int EPB  = 8192;                      // edges per hist block
static constexpr int NHB  = (NE + EPB - 1) / EPB;      // 196
static constexpr int NS   = NBUK * NHB;                // 153272 hist entries
static constexpr int SCAN_B = 256;
static constexpr int NSB  = (NS + SCAN_B - 1) / SCAN_B; // 599 (<=1024)
static constexpr int CAP  = 4096;                      // LDS edges per chunk

// ---- bf16 helpers (bit-level, RNE) ----
__device__ __forceinline__ float bflo(unsigned v) {
    return __uint_as_float((v & 0xFFFFu) << 16);
}
__device__ __forceinline__ float bfhi(unsigned v) {
    return __uint_as_float(v & 0xFFFF0000u);
}
__device__ __forceinline__ unsigned short f2bf(float f) {
    unsigned u = __float_as_uint(f);
    u += 0x7FFFu + ((u >> 16) & 1u);   // round to nearest even
    return (unsigned short)(u >> 16);
}

// ---------------------------------------------------------------------------
// H1 = relu(F @ W1 + b1), f32 in -> bf16 out
// ---------------------------------------------------------------------------
__global__ __launch_bounds__(256, 2)
void gemm1(const float* __restrict__ X, const float* __restrict__ W,
           const float* __restrict__ b, unsigned short* __restrict__ Y)
{
    __shared__ float Wl[128 * 128];   // 64 KB
    __shared__ float fr[8][128];
    __shared__ float bl[128];

    const int t = threadIdx.x;
    for (int i = t; i < (128 * 128) / 4; i += 256)
        reinterpret_cast<float4*>(Wl)[i] = reinterpret_cast<const float4*>(W)[i];
    if (t < 128) bl[t] = b[t];
    __syncthreads();

    const int nodeBase = blockIdx.x * 64;
    const int r  = t >> 5;
    const int jb = (t & 31) * 4;

    for (int p = 0; p < 8; ++p) {
        const int row0 = nodeBase + p * 8;
        if (row0 + r < NN)
            *reinterpret_cast<float4*>(&fr[r][jb]) =
                *reinterpret_cast<const float4*>(&X[(size_t)(row0 + r) * CH + jb]);
        __syncthreads();

        const int row = row0 + r;
        if (row < NN) {
            float a0 = bl[jb + 0], a1 = bl[jb + 1], a2 = bl[jb + 2], a3 = bl[jb + 3];
            #pragma unroll 16
            for (int k = 0; k < 128; ++k) {
                const float f = fr[r][k];
                const float4 w4 = *reinterpret_cast<const float4*>(&Wl[k * 128 + jb]);
                a0 += f * w4.x; a1 += f * w4.y; a2 += f * w4.z; a3 += f * w4.w;
            }
            ushort4 o;
            o.x = f2bf(fmaxf(a0, 0.f)); o.y = f2bf(fmaxf(a1, 0.f));
            o.z = f2bf(fmaxf(a2, 0.f)); o.w = f2bf(fmaxf(a3, 0.f));
            *reinterpret_cast<ushort4*>(&Y[(size_t)row * CH + jb]) = o;
        }
        __syncthreads();
    }
}

// ---------------------------------------------------------------------------
// Bucketing: per-block LDS histogram over 782 coarse buckets (src>>6)
// ---------------------------------------------------------------------------
__global__ __launch_bounds__(256)
void bucket_hist(const int* __restrict__ src, int* __restrict__ H)
{
    __shared__ int h[NBUK];
    const int t = threadIdx.x;
    for (int i = t; i < NBUK; i += 256) h[i] = 0;
    __syncthreads();
    const int e0 = blockIdx.x * EPB;
    for (int i = t; i < EPB; i += 256) {
        const int e = e0 + i;
        if (e < NE) atomicAdd(&h[src[e] >> 6], 1);
    }
    __syncthreads();
    for (int i = t; i < NBUK; i += 256) H[i * NHB + blockIdx.x] = h[i];
}

__global__ __launch_bounds__(SCAN_B)
void scan_local(int* __restrict__ H, int* __restrict__ bsum)
{
    __shared__ int buf[SCAN_B];
    const int t = threadIdx.x;
    const int g = blockIdx.x * SCAN_B + t;
    const int v = (g < NS) ? H[g] : 0;
    buf[t] = v;
    __syncthreads();
    #pragma unroll
    for (int off = 1; off < SCAN_B; off <<= 1) {
        const int x = (t >= off) ? buf[t - off] : 0;
        __syncthreads();
        buf[t] += x;
        __syncthreads();
    }
    if (g < NS) H[g] = buf[t] - v;
    if (t == SCAN_B - 1) bsum[blockIdx.x] = buf[t];
}

__global__ __launch_bounds__(1024)
void scan_bsums(int* __restrict__ bsum)
{
    __shared__ int buf[1024];
    const int t = threadIdx.x;
    const int v = (t < NSB) ? bsum[t] : 0;
    buf[t] = v;
    __syncthreads();
    #pragma unroll
    for (int off = 1; off < 1024; off <<= 1) {
        const int x = (t >= off) ? buf[t - off] : 0;
        __syncthreads();
        buf[t] += x;
        __syncthreads();
    }
    if (t < NSB) bsum[t] = buf[t] - v;
    if (t == 1023) bsum[NSB] = buf[t];
}

__global__ __launch_bounds__(SCAN_B)
void scan_add(int* __restrict__ H, const int* __restrict__ bsum)
{
    const int g = blockIdx.x * SCAN_B + threadIdx.x;
    if (g < NS) H[g] += bsum[blockIdx.x];
}

__global__ __launch_bounds__(256)
void bucket_scatter(const int* __restrict__ src, const int* __restrict__ dst,
                    const int* __restrict__ S, int* __restrict__ EP)
{
    __shared__ int cur[NBUK];
    const int t = threadIdx.x;
    for (int i = t; i < NBUK; i += 256) cur[i] = S[i * NHB + blockIdx.x];
    __syncthreads();
    const int e0 = blockIdx.x * EPB;
    for (int i = t; i < EPB; i += 256) {
        const int e = e0 + i;
        if (e < NE) {
            const int s = src[e];
            const int pos = atomicAdd(&cur[s >> 6], 1);
            EP[pos] = ((s & 63) << 16) | dst[e];
        }
    }
}

// ---------------------------------------------------------------------------
// Fused gather (bf16 rows): one block (512 thr, 8 waves) per bucket.
// LDS counting-sort by local node; wave w accumulates nodes [w*8, w*8+8).
// ---------------------------------------------------------------------------
template<bool WRITE_DEG>
__global__ __launch_bounds__(512)
void bucket_gather(const int* __restrict__ S, const int* __restrict__ EP,
                   const unsigned short* __restrict__ X,
                   unsigned short* __restrict__ Y, int* __restrict__ deg)
{
    __shared__ int raw[CAP];                 // 16 KB
    __shared__ unsigned short srt[CAP];      // 8 KB
    __shared__ int hist[NPB], cur[NPB], segBeg[NPB + 1], degSum[NPB];

    const int t = threadIdx.x;
    const int w = t >> 6;                    // 0..7
    const int lane = t & 63;
    const int b = blockIdx.x;
    const int node0 = b * NPB;
    const int nNodes = min(NPB, NN - node0);
    const int beg = S[b * NHB];
    const int end = (b == NBUK - 1) ? NE : S[(b + 1) * NHB];
    const int cbase = lane * 2;              // bf16 pair -> dword

    float2 acc[8];
    #pragma unroll
    for (int i = 0; i < 8; ++i) acc[i] = make_float2(0.f, 0.f);
    if (WRITE_DEG && t < NPB) degSum[t] = 0;

    for (int cbeg = beg; cbeg < end; cbeg += CAP) {
        const int C = min(CAP, end - cbeg);
        for (int i = t; i < C; i += 512) raw[i] = EP[cbeg + i];
        if (t < NPB) hist[t] = 0;
        __syncthreads();
        for (int i = t; i < C; i += 512) atomicAdd(&hist[raw[i] >> 16], 1);
        __syncthreads();
        if (t == 0) {
            int s = 0;
            for (int i = 0; i < NPB; ++i) { segBeg[i] = s; s += hist[i]; }
            segBeg[NPB] = s;
        }
        if (WRITE_DEG && t < NPB) degSum[t] += hist[t];
        __syncthreads();
        if (t < NPB) cur[t] = segBeg[t];
        __syncthreads();
        for (int i = t; i < C; i += 512) {
            const int p = raw[i];
            const int pos = atomicAdd(&cur[p >> 16], 1);
            srt[pos] = (unsigned short)(p & 0xFFFF);
        }
        __syncthreads();

        #pragma unroll
        for (int ni = 0; ni < 8; ++ni) {
            const int n = w * 8 + ni;
            if (n < nNodes) {
                const int sb = segBeg[n], se = segBeg[n + 1];
                float ax = acc[ni].x, ay = acc[ni].y;
                int i = sb;
                for (; i + 4 <= se; i += 4) {
                    const int d0 = srt[i], d1 = srt[i + 1], d2 = srt[i + 2], d3 = srt[i + 3];
                    const unsigned v0 = *reinterpret_cast<const unsigned*>(&X[(size_t)d0 * CH + cbase]);
                    const unsigned v1 = *reinterpret_cast<const unsigned*>(&X[(size_t)d1 * CH + cbase]);
                    const unsigned v2 = *reinterpret_cast<const unsigned*>(&X[(size_t)d2 * CH + cbase]);
                    const unsigned v3 = *reinterpret_cast<const unsigned*>(&X[(size_t)d3 * CH + cbase]);
                    ax += bflo(v0) + bflo(v1) + bflo(v2) + bflo(v3);
                    ay += bfhi(v0) + bfhi(v1) + bfhi(v2) + bfhi(v3);
                }
                for (; i < se; ++i) {
                    const unsigned v = *reinterpret_cast<const unsigned*>(&X[(size_t)srt[i] * CH + cbase]);
                    ax += bflo(v); ay += bfhi(v);
                }
                acc[ni].x = ax; acc[ni].y = ay;
            }
        }
        __syncthreads();
    }

    #pragma unroll
    for (int ni = 0; ni < 8; ++ni) {
        const int n = w * 8 + ni;
        if (n < nNodes) {
            const unsigned packed = ((unsigned)f2bf(acc[ni].y) << 16) | f2bf(acc[ni].x);
            *reinterpret_cast<unsigned*>(&Y[(size_t)(node0 + n) * CH + cbase]) = packed;
        }
    }
    if (WRITE_DEG && t < nNodes) deg[node0 + t] = degSum[t];
}

// ---------------------------------------------------------------------------
// small_prep: M = W2 @ Wfc (128x40), cfc = b2 @ Wfc (40). One block.
// ---------------------------------------------------------------------------
__global__ __launch_bounds__(256)
void small_prep(const float* __restrict__ W2, const float* __restrict__ Wfc,
                const float* __restrict__ b2, float* __restrict__ M,
                float* __restrict__ cfc)
{
    const int t = threadIdx.x;
    for (int idx = t; idx < 128 * NCLS; idx += 256) {
        const int k = idx / NCLS;
        const int c = idx % NCLS;
        float a = 0.f;
        #pragma unroll 8
        for (int j = 0; j < 128; ++j) a += W2[k * 128 + j] * Wfc[j * NCLS + c];
        M[idx] = a;
    }
    if (t < NCLS) {
        float a = 0.f;
        for (int j = 0; j < 128; ++j) a += b2[j] * Wfc[j * NCLS + t];
        cfc[t] = a;
    }
}

// ---------------------------------------------------------------------------
// out(N,40) = T(bf16) @ M + deg*cfc + bfc
// ---------------------------------------------------------------------------
__global__ __launch_bounds__(256)
void fc_tail(const unsigned short* __restrict__ T, const float* __restrict__ M,
             const float* __restrict__ cfc, const float* __restrict__ bfc,
             const int* __restrict__ deg, float* __restrict__ Y)
{
    __shared__ float Ml[128 * NCLS];  // 20 KB
    __shared__ float cl[NCLS], bl[NCLS];
    const int t = threadIdx.x;
    for (int i = t; i < 128 * NCLS; i += 256) Ml[i] = M[i];
    if (t < NCLS) { cl[t] = cfc[t]; bl[t] = bfc[t]; }
    __syncthreads();

    const int idx = blockIdx.x * 256 + t;
    if (idx >= NN * NCLS) return;
    const int row = idx / NCLS;
    const int c   = idx % NCLS;
    const unsigned* xr = reinterpret_cast<const unsigned*>(&T[(size_t)row * CH]);
    float acc = bl[c] + (float)deg[row] * cl[c];
    #pragma unroll 8
    for (int k = 0; k < 64; ++k) {
        const unsigned v = xr[k];
        acc += bflo(v) * Ml[(2 * k) * NCLS + c] + bfhi(v) * Ml[(2 * k + 1) * NCLS + c];
    }
    Y[idx] = acc;
}

extern "C" void kernel_launch(void* const* d_in, const int* in_sizes, int n_in,
                              void* d_out, int out_size, void* d_ws, size_t ws_size,
                              hipStream_t stream) {
    const float* F   = (const float*)d_in[0];  // (1,N,128)
    const int*   EI  = (const int*)  d_in[1];  // (1,2,E) int32
    const float* W1  = (const float*)d_in[3];
    const float* b1  = (const float*)d_in[4];
    const float* W2  = (const float*)d_in[5];
    const float* b2  = (const float*)d_in[6];
    const float* Wfc = (const float*)d_in[7];
    const float* bfc = (const float*)d_in[8];
    float* out = (float*)d_out;

    char* ws = (char*)d_ws;
    unsigned short* A = (unsigned short*)(ws);                 // bf16, 12.8 MB
    unsigned short* B = (unsigned short*)(ws + BF_BYTES);      // bf16, 12.8 MB
    int*   EP   = (int*)  (ws + 2 * BF_BYTES);                 // NE ints (6.4 MB)
    int*   H    = EP   + NE;                                   // NS ints
    int*   bsum = H    + NS;                                   // NSB+1
    int*   deg  = bsum + NSB + 1;                              // NN
    float* M    = (float*)(deg + NN);                          // 128*40
    float* cfc  = M + 128 * NCLS;                              // 40

    const int* src = EI;          // edge_index[0,:]
    const int* dst = EI + NE;     // edge_index[1,:]

    // ---- bucket edges by src>>6 ----
    bucket_hist<<<NHB, 256, 0, stream>>>(src, H);
    scan_local<<<NSB, SCAN_B, 0, stream>>>(H, bsum);
    scan_bsums<<<1, 1024, 0, stream>>>(bsum);
    scan_add<<<NSB, SCAN_B, 0, stream>>>(H, bsum);
    bucket_scatter<<<NHB, 256, 0, stream>>>(src, dst, H, EP);

    // ---- tail-weight precompute (independent) ----
    small_prep<<<1, 256, 0, stream>>>(W2, Wfc, b2, M, cfc);

    // ---- H1 = relu(F @ W1 + b1) -> A (bf16) ----
    gemm1<<<(NN + 63) / 64, 256, 0, stream>>>(F, W1, b1, A);

    // ---- S1 = gather-sum(A) -> B (+deg) ----
    bucket_gather<true><<<NBUK, 512, 0, stream>>>(H, EP, A, B, deg);

    // ---- T = gather-sum(B) -> A ----
    bucket_gather<false><<<NBUK, 512, 0, stream>>>(H, EP, B, A, nullptr);

    // ---- out = T @ M + deg*cfc + bfc ----
    fc_tail<<<(NN * NCLS + 255) / 256, 256, 0, stream>>>(A, M, cfc, bfc, deg, out);
}

// Round 6
// 249.101 us; speedup vs baseline: 11.3773x; 1.3006x over previous
//
#include <hip/hip_runtime.h>

static constexpr int NN = 50000;    // nodes
static constexpr int NE = 1600000;  // edges
static constexpr int CH = 128;
static constexpr int NCLS = 40;
static constexpr size_t BF_BYTES = (size_t)NN * CH * 2;   // 12.8 MB bf16 matrix

static constexpr int NPB  = 64;                        // nodes per bucket
static constexpr int NBUK = (NN + NPB - 1) / NPB;      // 782
static constexpr int EPB  = 8192;                      // edges per hist block
static constexpr int NHB  = (NE + EPB - 1) / EPB;      // 196
static constexpr int NS   = NBUK * NHB;                // 153272 hist entries
static constexpr int SCAN_B = 256;
static constexpr int NSB  = (NS + SCAN_B - 1) / SCAN_B; // 599 (<=1024)
static constexpr int CAP  = 4096;                      // LDS edges per chunk

// ---- bf16 helpers (bit-level, RNE) ----
__device__ __forceinline__ float bflo(unsigned v) {
    return __uint_as_float((v & 0xFFFFu) << 16);
}
__device__ __forceinline__ float bfhi(unsigned v) {
    return __uint_as_float(v & 0xFFFF0000u);
}
__device__ __forceinline__ unsigned short f2bf(float f) {
    unsigned u = __float_as_uint(f);
    u += 0x7FFFu + ((u >> 16) & 1u);   // round to nearest even
    return (unsigned short)(u >> 16);
}

// ---------------------------------------------------------------------------
// H1 = relu(F @ W1 + b1), f32 in -> bf16 out
// ---------------------------------------------------------------------------
__global__ __launch_bounds__(256, 2)
void gemm1(const float* __restrict__ X, const float* __restrict__ W,
           const float* __restrict__ b, unsigned short* __restrict__ Y)
{
    __shared__ float Wl[128 * 128];   // 64 KB
    __shared__ float fr[8][128];
    __shared__ float bl[128];

    const int t = threadIdx.x;
    for (int i = t; i < (128 * 128) / 4; i += 256)
        reinterpret_cast<float4*>(Wl)[i] = reinterpret_cast<const float4*>(W)[i];
    if (t < 128) bl[t] = b[t];
    __syncthreads();

    const int nodeBase = blockIdx.x * 64;
    const int r  = t >> 5;
    const int jb = (t & 31) * 4;

    for (int p = 0; p < 8; ++p) {
        const int row0 = nodeBase + p * 8;
        if (row0 + r < NN)
            *reinterpret_cast<float4*>(&fr[r][jb]) =
                *reinterpret_cast<const float4*>(&X[(size_t)(row0 + r) * CH + jb]);
        __syncthreads();

        const int row = row0 + r;
        if (row < NN) {
            float a0 = bl[jb + 0], a1 = bl[jb + 1], a2 = bl[jb + 2], a3 = bl[jb + 3];
            #pragma unroll 16
            for (int k = 0; k < 128; ++k) {
                const float f = fr[r][k];
                const float4 w4 = *reinterpret_cast<const float4*>(&Wl[k * 128 + jb]);
                a0 += f * w4.x; a1 += f * w4.y; a2 += f * w4.z; a3 += f * w4.w;
            }
            ushort4 o;
            o.x = f2bf(fmaxf(a0, 0.f)); o.y = f2bf(fmaxf(a1, 0.f));
            o.z = f2bf(fmaxf(a2, 0.f)); o.w = f2bf(fmaxf(a3, 0.f));
            *reinterpret_cast<ushort4*>(&Y[(size_t)row * CH + jb]) = o;
        }
        __syncthreads();
    }
}

// ---------------------------------------------------------------------------
// Bucketing: per-block LDS histogram over 782 coarse buckets (src>>6)
// ---------------------------------------------------------------------------
__global__ __launch_bounds__(256)
void bucket_hist(const int* __restrict__ src, int* __restrict__ H)
{
    __shared__ int h[NBUK];
    const int t = threadIdx.x;
    for (int i = t; i < NBUK; i += 256) h[i] = 0;
    __syncthreads();
    const int e0 = blockIdx.x * EPB;
    for (int i = t; i < EPB; i += 256) {
        const int e = e0 + i;
        if (e < NE) atomicAdd(&h[src[e] >> 6], 1);
    }
    __syncthreads();
    for (int i = t; i < NBUK; i += 256) H[i * NHB + blockIdx.x] = h[i];
}

__global__ __launch_bounds__(SCAN_B)
void scan_local(int* __restrict__ H, int* __restrict__ bsum)
{
    __shared__ int buf[SCAN_B];
    const int t = threadIdx.x;
    const int g = blockIdx.x * SCAN_B + t;
    const int v = (g < NS) ? H[g] : 0;
    buf[t] = v;
    __syncthreads();
    #pragma unroll
    for (int off = 1; off < SCAN_B; off <<= 1) {
        const int x = (t >= off) ? buf[t - off] : 0;
        __syncthreads();
        buf[t] += x;
        __syncthreads();
    }
    if (g < NS) H[g] = buf[t] - v;
    if (t == SCAN_B - 1) bsum[blockIdx.x] = buf[t];
}

__global__ __launch_bounds__(1024)
void scan_bsums(int* __restrict__ bsum)
{
    __shared__ int buf[1024];
    const int t = threadIdx.x;
    const int v = (t < NSB) ? bsum[t] : 0;
    buf[t] = v;
    __syncthreads();
    #pragma unroll
    for (int off = 1; off < 1024; off <<= 1) {
        const int x = (t >= off) ? buf[t - off] : 0;
        __syncthreads();
        buf[t] += x;
        __syncthreads();
    }
    if (t < NSB) bsum[t] = buf[t] - v;
    if (t == 1023) bsum[NSB] = buf[t];
}

__global__ __launch_bounds__(SCAN_B)
void scan_add(int* __restrict__ H, const int* __restrict__ bsum)
{
    const int g = blockIdx.x * SCAN_B + threadIdx.x;
    if (g < NS) H[g] += bsum[blockIdx.x];
}

__global__ __launch_bounds__(256)
void bucket_scatter(const int* __restrict__ src, const int* __restrict__ dst,
                    const int* __restrict__ S, int* __restrict__ EP)
{
    __shared__ int cur[NBUK];
    const int t = threadIdx.x;
    for (int i = t; i < NBUK; i += 256) cur[i] = S[i * NHB + blockIdx.x];
    __syncthreads();
    const int e0 = blockIdx.x * EPB;
    for (int i = t; i < EPB; i += 256) {
        const int e = e0 + i;
        if (e < NE) {
            const int s = src[e];
            const int pos = atomicAdd(&cur[s >> 6], 1);
            EP[pos] = ((s & 63) << 16) | dst[e];
        }
    }
}

// ---------------------------------------------------------------------------
// Fused gather (bf16 rows): one block (512 thr, 8 waves) per bucket.
// ---------------------------------------------------------------------------
template<bool WRITE_DEG>
__global__ __launch_bounds__(512)
void bucket_gather(const int* __restrict__ S, const int* __restrict__ EP,
                   const unsigned short* __restrict__ X,
                   unsigned short* __restrict__ Y, int* __restrict__ deg)
{
    __shared__ int raw[CAP];                 // 16 KB
    __shared__ unsigned short srt[CAP];      // 8 KB
    __shared__ int hist[NPB], cur[NPB], segBeg[NPB + 1], degSum[NPB];

    const int t = threadIdx.x;
    const int w = t >> 6;                    // 0..7
    const int lane = t & 63;
    const int b = blockIdx.x;
    const int node0 = b * NPB;
    const int nNodes = min(NPB, NN - node0);
    const int beg = S[b * NHB];
    const int end = (b == NBUK - 1) ? NE : S[(b + 1) * NHB];
    const int cbase = lane * 2;              // bf16 pair -> dword

    float2 acc[8];
    #pragma unroll
    for (int i = 0; i < 8; ++i) acc[i] = make_float2(0.f, 0.f);
    if (WRITE_DEG && t < NPB) degSum[t] = 0;

    for (int cbeg = beg; cbeg < end; cbeg += CAP) {
        const int C = min(CAP, end - cbeg);
        for (int i = t; i < C; i += 512) raw[i] = EP[cbeg + i];
        if (t < NPB) hist[t] = 0;
        __syncthreads();
        for (int i = t; i < C; i += 512) atomicAdd(&hist[raw[i] >> 16], 1);
        __syncthreads();
        if (t == 0) {
            int s = 0;
            for (int i = 0; i < NPB; ++i) { segBeg[i] = s; s += hist[i]; }
            segBeg[NPB] = s;
        }
        if (WRITE_DEG && t < NPB) degSum[t] += hist[t];
        __syncthreads();
        if (t < NPB) cur[t] = segBeg[t];
        __syncthreads();
        for (int i = t; i < C; i += 512) {
            const int p = raw[i];
            const int pos = atomicAdd(&cur[p >> 16], 1);
            srt[pos] = (unsigned short)(p & 0xFFFF);
        }
        __syncthreads();

        #pragma unroll
        for (int ni = 0; ni < 8; ++ni) {
            const int n = w * 8 + ni;
            if (n < nNodes) {
                const int sb = segBeg[n], se = segBeg[n + 1];
                float ax = acc[ni].x, ay = acc[ni].y;
                int i = sb;
                for (; i + 4 <= se; i += 4) {
                    const int d0 = srt[i], d1 = srt[i + 1], d2 = srt[i + 2], d3 = srt[i + 3];
                    const unsigned v0 = *reinterpret_cast<const unsigned*>(&X[(size_t)d0 * CH + cbase]);
                    const unsigned v1 = *reinterpret_cast<const unsigned*>(&X[(size_t)d1 * CH + cbase]);
                    const unsigned v2 = *reinterpret_cast<const unsigned*>(&X[(size_t)d2 * CH + cbase]);
                    const unsigned v3 = *reinterpret_cast<const unsigned*>(&X[(size_t)d3 * CH + cbase]);
                    ax += bflo(v0) + bflo(v1) + bflo(v2) + bflo(v3);
                    ay += bfhi(v0) + bfhi(v1) + bfhi(v2) + bfhi(v3);
                }
                for (; i < se; ++i) {
                    const unsigned v = *reinterpret_cast<const unsigned*>(&X[(size_t)srt[i] * CH + cbase]);
                    ax += bflo(v); ay += bfhi(v);
                }
                acc[ni].x = ax; acc[ni].y = ay;
            }
        }
        __syncthreads();
    }

    #pragma unroll
    for (int ni = 0; ni < 8; ++ni) {
        const int n = w * 8 + ni;
        if (n < nNodes) {
            const unsigned packed = ((unsigned)f2bf(acc[ni].y) << 16) | f2bf(acc[ni].x);
            *reinterpret_cast<unsigned*>(&Y[(size_t)(node0 + n) * CH + cbase]) = packed;
        }
    }
    if (WRITE_DEG && t < nNodes) deg[node0 + t] = degSum[t];
}

// ---------------------------------------------------------------------------
// small_prep: M = W2 @ Wfc (128x40), cfc = b2 @ Wfc (40).
// 20 blocks, one output element per thread (was 1 block / 100 us!).
// ---------------------------------------------------------------------------
__global__ __launch_bounds__(256)
void small_prep(const float* __restrict__ W2, const float* __restrict__ Wfc,
                const float* __restrict__ b2, float* __restrict__ M,
                float* __restrict__ cfc)
{
    const int idx = blockIdx.x * 256 + threadIdx.x;
    if (idx < 128 * NCLS) {
        const int k = idx / NCLS;
        const int c = idx % NCLS;
        float a = 0.f;
        #pragma unroll 16
        for (int j = 0; j < 128; ++j) a += W2[k * 128 + j] * Wfc[j * NCLS + c];
        M[idx] = a;
    }
    if (blockIdx.x == 0 && threadIdx.x < NCLS) {
        const int c = threadIdx.x;
        float a = 0.f;
        #pragma unroll 16
        for (int j = 0; j < 128; ++j) a += b2[j] * Wfc[j * NCLS + c];
        cfc[c] = a;
    }
}

// ---------------------------------------------------------------------------
// out(N,40) = T(bf16) @ M + deg*cfc + bfc
// ---------------------------------------------------------------------------
__global__ __launch_bounds__(256)
void fc_tail(const unsigned short* __restrict__ T, const float* __restrict__ M,
             const float* __restrict__ cfc, const float* __restrict__ bfc,
             const int* __restrict__ deg, float* __restrict__ Y)
{
    __shared__ float Ml[128 * NCLS];  // 20 KB
    __shared__ float cl[NCLS], bl[NCLS];
    const int t = threadIdx.x;
    for (int i = t; i < 128 * NCLS; i += 256) Ml[i] = M[i];
    if (t < NCLS) { cl[t] = cfc[t]; bl[t] = bfc[t]; }
    __syncthreads();

    const int idx = blockIdx.x * 256 + t;
    if (idx >= NN * NCLS) return;
    const int row = idx / NCLS;
    const int c   = idx % NCLS;
    const unsigned* xr = reinterpret_cast<const unsigned*>(&T[(size_t)row * CH]);
    float acc = bl[c] + (float)deg[row] * cl[c];
    #pragma unroll 8
    for (int k = 0; k < 64; ++k) {
        const unsigned v = xr[k];
        acc += bflo(v) * Ml[(2 * k) * NCLS + c] + bfhi(v) * Ml[(2 * k + 1) * NCLS + c];
    }
    Y[idx] = acc;
}

extern "C" void kernel_launch(void* const* d_in, const int* in_sizes, int n_in,
                              void* d_out, int out_size, void* d_ws, size_t ws_size,
                              hipStream_t stream) {
    const float* F   = (const float*)d_in[0];  // (1,N,128)
    const int*   EI  = (const int*)  d_in[1];  // (1,2,E) int32
    const float* W1  = (const float*)d_in[3];
    const float* b1  = (const float*)d_in[4];
    const float* W2  = (const float*)d_in[5];
    const float* b2  = (const float*)d_in[6];
    const float* Wfc = (const float*)d_in[7];
    const float* bfc = (const float*)d_in[8];
    float* out = (float*)d_out;

    char* ws = (char*)d_ws;
    unsigned short* A = (unsigned short*)(ws);                 // bf16, 12.8 MB
    unsigned short* B = (unsigned short*)(ws + BF_BYTES);      // bf16, 12.8 MB
    int*   EP   = (int*)  (ws + 2 * BF_BYTES);                 // NE ints (6.4 MB)
    int*   H    = EP   + NE;                                   // NS ints
    int*   bsum = H    + NS;                                   // NSB+1
    int*   deg  = bsum + NSB + 1;                              // NN
    float* M    = (float*)(deg + NN);                          // 128*40
    float* cfc  = M + 128 * NCLS;                              // 40

    const int* src = EI;          // edge_index[0,:]
    const int* dst = EI + NE;     // edge_index[1,:]

    // ---- bucket edges by src>>6 ----
    bucket_hist<<<NHB, 256, 0, stream>>>(src, H);
    scan_local<<<NSB, SCAN_B, 0, stream>>>(H, bsum);
    scan_bsums<<<1, 1024, 0, stream>>>(bsum);
    scan_add<<<NSB, SCAN_B, 0, stream>>>(H, bsum);
    bucket_scatter<<<NHB, 256, 0, stream>>>(src, dst, H, EP);

    // ---- tail-weight precompute ----
    small_prep<<<(128 * NCLS + 255) / 256, 256, 0, stream>>>(W2, Wfc, b2, M, cfc);

    // ---- H1 = relu(F @ W1 + b1) -> A (bf16) ----
    gemm1<<<(NN + 63) / 64, 256, 0, stream>>>(F, W1, b1, A);

    // ---- S1 = gather-sum(A) -> B (+deg) ----
    bucket_gather<true><<<NBUK, 512, 0, stream>>>(H, EP, A, B, deg);

    // ---- T = gather-sum(B) -> A ----
    bucket_gather<false><<<NBUK, 512, 0, stream>>>(H, EP, B, A, nullptr);

    // ---- out = T @ M + deg*cfc + bfc ----
    fc_tail<<<(NN * NCLS + 255) / 256, 256, 0, stream>>>(A, M, cfc, bfc, deg, out);
}

// Round 7
// 213.957 us; speedup vs baseline: 13.2462x; 1.1643x over previous
//
#include <hip/hip_runtime.h>

static constexpr int NN = 50000;    // nodes
static constexpr int NE = 1600000;  // edges
static constexpr int CH = 128;
static constexpr int NCLS = 40;
static constexpr size_t BF_BYTES = (size_t)NN * CH * 2;   // 12.8 MB bf16 matrix

static constexpr int NPB  = 64;                        // nodes per bucket
static constexpr int NBUK = (NN + NPB - 1) / NPB;      // 782
static constexpr int EPB  = 8192;                      // edges per hist block
static constexpr int NHB  = (NE + EPB - 1) / EPB;      // 196
static constexpr int NS   = NBUK * NHB;                // 153272 hist entries
static constexpr int SCAN_B = 256;
static constexpr int NSB  = (NS + SCAN_B - 1) / SCAN_B; // 599 (<=1024)
static constexpr int CAP  = 4096;                      // LDS edges per chunk

typedef __attribute__((ext_vector_type(8))) short bf16x8;
typedef __attribute__((ext_vector_type(4))) float f32x4;

// ---- bf16 helpers (bit-level, RNE) ----
__device__ __forceinline__ float bflo(unsigned v) {
    return __uint_as_float((v & 0xFFFFu) << 16);
}
__device__ __forceinline__ float bfhi(unsigned v) {
    return __uint_as_float(v & 0xFFFF0000u);
}
__device__ __forceinline__ unsigned short f2bf(float f) {
    unsigned u = __float_as_uint(f);
    u += 0x7FFFu + ((u >> 16) & 1u);   // round to nearest even
    return (unsigned short)(u >> 16);
}

// ---------------------------------------------------------------------------
// H1 = relu(F @ W1 + b1) via bf16 MFMA. Block: 256 thr (4 waves), 64 rows.
// Wave w: rows [16w,16w+16) x 128 cols = 8 tiles of 16x16, K=128 in 4 steps.
// Frag k-layout (m156-verified): elem i -> k = 4*(lane>>4) + (i&3) + 16*(i>>2).
// ---------------------------------------------------------------------------
__global__ __launch_bounds__(256)
void gemm1_mfma(const float* __restrict__ X, const float* __restrict__ W,
                const float* __restrict__ b, unsigned short* __restrict__ Y)
{
    constexpr int PAD = 136;                       // bank-spread + 16B-aligned rows
    __shared__ unsigned short Wt[128 * PAD];       // W1^T bf16 [c][k], 34.8 KB
    __shared__ unsigned short Fa[64 * PAD];        // F tile bf16 [r][k], 17.4 KB
    __shared__ float bl[128];

    const int t = threadIdx.x;
    const int lane = t & 63;
    const int w = t >> 6;

    // ---- stage Wt = W1^T (bf16) ----
    {
        const int k = t >> 1;
        const int c0 = (t & 1) * 64;
        #pragma unroll 4
        for (int j = 0; j < 64; j += 4) {
            const float4 v = *reinterpret_cast<const float4*>(&W[k * 128 + c0 + j]);
            Wt[(c0 + j + 0) * PAD + k] = f2bf(v.x);
            Wt[(c0 + j + 1) * PAD + k] = f2bf(v.y);
            Wt[(c0 + j + 2) * PAD + k] = f2bf(v.z);
            Wt[(c0 + j + 3) * PAD + k] = f2bf(v.w);
        }
    }
    if (t < 128) bl[t] = b[t];

    // ---- stage Fa (f32 -> bf16) ----
    const int base = blockIdx.x * 64;
    const int nRows = min(64, NN - base);
    {
        const int r = t >> 2;
        const int c0 = (t & 3) * 32;
        if (r < nRows) {
            #pragma unroll
            for (int j = 0; j < 32; j += 4) {
                const float4 v = *reinterpret_cast<const float4*>(&X[(size_t)(base + r) * CH + c0 + j]);
                ushort4 o; o.x = f2bf(v.x); o.y = f2bf(v.y); o.z = f2bf(v.z); o.w = f2bf(v.w);
                *reinterpret_cast<ushort4*>(&Fa[r * PAD + c0 + j]) = o;
            }
        } else {
            #pragma unroll
            for (int j = 0; j < 32; j += 4) {
                ushort4 z; z.x = z.y = z.z = z.w = 0;
                *reinterpret_cast<ushort4*>(&Fa[r * PAD + c0 + j]) = z;
            }
        }
    }
    __syncthreads();

    // ---- MFMA compute ----
    f32x4 acc[8];
    #pragma unroll
    for (int i = 0; i < 8; ++i) acc[i] = (f32x4){0.f, 0.f, 0.f, 0.f};

    const int arow = w * 16 + (lane & 15);
    const int kgrp = (lane >> 4) * 4;

    #pragma unroll
    for (int ks = 0; ks < 4; ++ks) {
        const int k0 = ks * 32 + kgrp;
        bf16x8 af;
        {
            const short4 lo = *reinterpret_cast<const short4*>(&Fa[arow * PAD + k0]);
            const short4 hi = *reinterpret_cast<const short4*>(&Fa[arow * PAD + k0 + 16]);
            af[0] = lo.x; af[1] = lo.y; af[2] = lo.z; af[3] = lo.w;
            af[4] = hi.x; af[5] = hi.y; af[6] = hi.z; af[7] = hi.w;
        }
        #pragma unroll
        for (int ct = 0; ct < 8; ++ct) {
            const int c = ct * 16 + (lane & 15);
            bf16x8 bf;
            const short4 lo = *reinterpret_cast<const short4*>(&Wt[c * PAD + k0]);
            const short4 hi = *reinterpret_cast<const short4*>(&Wt[c * PAD + k0 + 16]);
            bf[0] = lo.x; bf[1] = lo.y; bf[2] = lo.z; bf[3] = lo.w;
            bf[4] = hi.x; bf[5] = hi.y; bf[6] = hi.z; bf[7] = hi.w;
            acc[ct] = __builtin_amdgcn_mfma_f32_16x16x32_bf16(af, bf, acc[ct], 0, 0, 0);
        }
    }
    __syncthreads();   // Fa consumed; reuse as output staging

    // ---- bias + relu, stash bf16 tile back into Fa ----
    // C/D layout (m89-verified): col = lane&15, row = 4*(lane>>4) + reg
    #pragma unroll
    for (int ct = 0; ct < 8; ++ct) {
        const int c = ct * 16 + (lane & 15);
        const float bias = bl[c];
        #pragma unroll
        for (int r = 0; r < 4; ++r) {
            const int row = w * 16 + (lane >> 4) * 4 + r;
            Fa[row * PAD + c] = f2bf(fmaxf(acc[ct][r] + bias, 0.f));
        }
    }
    __syncthreads();

    // ---- coalesced bf16 write-out ----
    {
        const int r = t >> 2;
        const int c0 = (t & 3) * 32;
        if (r < nRows) {
            #pragma unroll
            for (int j = 0; j < 32; j += 8) {
                const ulong2 v = *reinterpret_cast<const ulong2*>(&Fa[r * PAD + c0 + j]);
                *reinterpret_cast<ulong2*>(&Y[(size_t)(base + r) * CH + c0 + j]) = v;
            }
        }
    }
}

// ---------------------------------------------------------------------------
// Bucketing: per-block LDS histogram over 782 coarse buckets (src>>6)
// ---------------------------------------------------------------------------
__global__ __launch_bounds__(256)
void bucket_hist(const int* __restrict__ src, int* __restrict__ H)
{
    __shared__ int h[NBUK];
    const int t = threadIdx.x;
    for (int i = t; i < NBUK; i += 256) h[i] = 0;
    __syncthreads();
    const int e0 = blockIdx.x * EPB;
    for (int i = t; i < EPB; i += 256) {
        const int e = e0 + i;
        if (e < NE) atomicAdd(&h[src[e] >> 6], 1);
    }
    __syncthreads();
    for (int i = t; i < NBUK; i += 256) H[i * NHB + blockIdx.x] = h[i];
}

__global__ __launch_bounds__(SCAN_B)
void scan_local(int* __restrict__ H, int* __restrict__ bsum)
{
    __shared__ int buf[SCAN_B];
    const int t = threadIdx.x;
    const int g = blockIdx.x * SCAN_B + t;
    const int v = (g < NS) ? H[g] : 0;
    buf[t] = v;
    __syncthreads();
    #pragma unroll
    for (int off = 1; off < SCAN_B; off <<= 1) {
        const int x = (t >= off) ? buf[t - off] : 0;
        __syncthreads();
        buf[t] += x;
        __syncthreads();
    }
    if (g < NS) H[g] = buf[t] - v;
    if (t == SCAN_B - 1) bsum[blockIdx.x] = buf[t];
}

__global__ __launch_bounds__(1024)
void scan_bsums(int* __restrict__ bsum)
{
    __shared__ int buf[1024];
    const int t = threadIdx.x;
    const int v = (t < NSB) ? bsum[t] : 0;
    buf[t] = v;
    __syncthreads();
    #pragma unroll
    for (int off = 1; off < 1024; off <<= 1) {
        const int x = (t >= off) ? buf[t - off] : 0;
        __syncthreads();
        buf[t] += x;
        __syncthreads();
    }
    if (t < NSB) bsum[t] = buf[t] - v;
    if (t == 1023) bsum[NSB] = buf[t];
}

__global__ __launch_bounds__(SCAN_B)
void scan_add(int* __restrict__ H, const int* __restrict__ bsum)
{
    const int g = blockIdx.x * SCAN_B + threadIdx.x;
    if (g < NS) H[g] += bsum[blockIdx.x];
}

__global__ __launch_bounds__(256)
void bucket_scatter(const int* __restrict__ src, const int* __restrict__ dst,
                    const int* __restrict__ S, int* __restrict__ EP)
{
    __shared__ int cur[NBUK];
    const int t = threadIdx.x;
    for (int i = t; i < NBUK; i += 256) cur[i] = S[i * NHB + blockIdx.x];
    __syncthreads();
    const int e0 = blockIdx.x * EPB;
    for (int i = t; i < EPB; i += 256) {
        const int e = e0 + i;
        if (e < NE) {
            const int s = src[e];
            const int pos = atomicAdd(&cur[s >> 6], 1);
            EP[pos] = ((s & 63) << 16) | dst[e];
        }
    }
}

// ---------------------------------------------------------------------------
// Fused gather (bf16 rows): one block (512 thr, 8 waves) per bucket.
// ---------------------------------------------------------------------------
template<bool WRITE_DEG>
__global__ __launch_bounds__(512)
void bucket_gather(const int* __restrict__ S, const int* __restrict__ EP,
                   const unsigned short* __restrict__ X,
                   unsigned short* __restrict__ Y, int* __restrict__ deg)
{
    __shared__ int raw[CAP];                 // 16 KB
    __shared__ unsigned short srt[CAP];      // 8 KB
    __shared__ int hist[NPB], cur[NPB], segBeg[NPB + 1], degSum[NPB];

    const int t = threadIdx.x;
    const int w = t >> 6;                    // 0..7
    const int lane = t & 63;
    const int b = blockIdx.x;
    const int node0 = b * NPB;
    const int nNodes = min(NPB, NN - node0);
    const int beg = S[b * NHB];
    const int end = (b == NBUK - 1) ? NE : S[(b + 1) * NHB];
    const int cbase = lane * 2;              // bf16 pair -> dword

    float2 acc[8];
    #pragma unroll
    for (int i = 0; i < 8; ++i) acc[i] = make_float2(0.f, 0.f);
    if (WRITE_DEG && t < NPB) degSum[t] = 0;

    for (int cbeg = beg; cbeg < end; cbeg += CAP) {
        const int C = min(CAP, end - cbeg);
        for (int i = t; i < C; i += 512) raw[i] = EP[cbeg + i];
        if (t < NPB) hist[t] = 0;
        __syncthreads();
        for (int i = t; i < C; i += 512) atomicAdd(&hist[raw[i] >> 16], 1);
        __syncthreads();
        if (t == 0) {
            int s = 0;
            for (int i = 0; i < NPB; ++i) { segBeg[i] = s; s += hist[i]; }
            segBeg[NPB] = s;
        }
        if (WRITE_DEG && t < NPB) degSum[t] += hist[t];
        __syncthreads();
        if (t < NPB) cur[t] = segBeg[t];
        __syncthreads();
        for (int i = t; i < C; i += 512) {
            const int p = raw[i];
            const int pos = atomicAdd(&cur[p >> 16], 1);
            srt[pos] = (unsigned short)(p & 0xFFFF);
        }
        __syncthreads();

        #pragma unroll
        for (int ni = 0; ni < 8; ++ni) {
            const int n = w * 8 + ni;
            if (n < nNodes) {
                const int sb = segBeg[n], se = segBeg[n + 1];
                float ax = acc[ni].x, ay = acc[ni].y;
                int i = sb;
                for (; i + 4 <= se; i += 4) {
                    const int d0 = srt[i], d1 = srt[i + 1], d2 = srt[i + 2], d3 = srt[i + 3];
                    const unsigned v0 = *reinterpret_cast<const unsigned*>(&X[(size_t)d0 * CH + cbase]);
                    const unsigned v1 = *reinterpret_cast<const unsigned*>(&X[(size_t)d1 * CH + cbase]);
                    const unsigned v2 = *reinterpret_cast<const unsigned*>(&X[(size_t)d2 * CH + cbase]);
                    const unsigned v3 = *reinterpret_cast<const unsigned*>(&X[(size_t)d3 * CH + cbase]);
                    ax += bflo(v0) + bflo(v1) + bflo(v2) + bflo(v3);
                    ay += bfhi(v0) + bfhi(v1) + bfhi(v2) + bfhi(v3);
                }
                for (; i < se; ++i) {
                    const unsigned v = *reinterpret_cast<const unsigned*>(&X[(size_t)srt[i] * CH + cbase]);
                    ax += bflo(v); ay += bfhi(v);
                }
                acc[ni].x = ax; acc[ni].y = ay;
            }
        }
        __syncthreads();
    }

    #pragma unroll
    for (int ni = 0; ni < 8; ++ni) {
        const int n = w * 8 + ni;
        if (n < nNodes) {
            const unsigned packed = ((unsigned)f2bf(acc[ni].y) << 16) | f2bf(acc[ni].x);
            *reinterpret_cast<unsigned*>(&Y[(size_t)(node0 + n) * CH + cbase]) = packed;
        }
    }
    if (WRITE_DEG && t < nNodes) deg[node0 + t] = degSum[t];
}

// ---------------------------------------------------------------------------
// small_prep: M = W2 @ Wfc (128x40), cfc = b2 @ Wfc (40). 20 blocks.
// ---------------------------------------------------------------------------
__global__ __launch_bounds__(256)
void small_prep(const float* __restrict__ W2, const float* __restrict__ Wfc,
                const float* __restrict__ b2, float* __restrict__ M,
                float* __restrict__ cfc)
{
    const int idx = blockIdx.x * 256 + threadIdx.x;
    if (idx < 128 * NCLS) {
        const int k = idx / NCLS;
        const int c = idx % NCLS;
        float a = 0.f;
        #pragma unroll 16
        for (int j = 0; j < 128; ++j) a += W2[k * 128 + j] * Wfc[j * NCLS + c];
        M[idx] = a;
    }
    if (blockIdx.x == 0 && threadIdx.x < NCLS) {
        const int c = threadIdx.x;
        float a = 0.f;
        #pragma unroll 16
        for (int j = 0; j < 128; ++j) a += b2[j] * Wfc[j * NCLS + c];
        cfc[c] = a;
    }
}

// ---------------------------------------------------------------------------
// out(N,40) = T(bf16) @ M + deg*cfc + bfc
// ---------------------------------------------------------------------------
__global__ __launch_bounds__(256)
void fc_tail(const unsigned short* __restrict__ T, const float* __restrict__ M,
             const float* __restrict__ cfc, const float* __restrict__ bfc,
             const int* __restrict__ deg, float* __restrict__ Y)
{
    __shared__ float Ml[128 * NCLS];  // 20 KB
    __shared__ float cl[NCLS], bl[NCLS];
    const int t = threadIdx.x;
    for (int i = t; i < 128 * NCLS; i += 256) Ml[i] = M[i];
    if (t < NCLS) { cl[t] = cfc[t]; bl[t] = bfc[t]; }
    __syncthreads();

    const int idx = blockIdx.x * 256 + t;
    if (idx >= NN * NCLS) return;
    const int row = idx / NCLS;
    const int c   = idx % NCLS;
    const unsigned* xr = reinterpret_cast<const unsigned*>(&T[(size_t)row * CH]);
    float acc = bl[c] + (float)deg[row] * cl[c];
    #pragma unroll 8
    for (int k = 0; k < 64; ++k) {
        const unsigned v = xr[k];
        acc += bflo(v) * Ml[(2 * k) * NCLS + c] + bfhi(v) * Ml[(2 * k + 1) * NCLS + c];
    }
    Y[idx] = acc;
}

extern "C" void kernel_launch(void* const* d_in, const int* in_sizes, int n_in,
                              void* d_out, int out_size, void* d_ws, size_t ws_size,
                              hipStream_t stream) {
    const float* F   = (const float*)d_in[0];  // (1,N,128)
    const int*   EI  = (const int*)  d_in[1];  // (1,2,E) int32
    const float* W1  = (const float*)d_in[3];
    const float* b1  = (const float*)d_in[4];
    const float* W2  = (const float*)d_in[5];
    const float* b2  = (const float*)d_in[6];
    const float* Wfc = (const float*)d_in[7];
    const float* bfc = (const float*)d_in[8];
    float* out = (float*)d_out;

    char* ws = (char*)d_ws;
    unsigned short* A = (unsigned short*)(ws);                 // bf16, 12.8 MB
    unsigned short* B = (unsigned short*)(ws + BF_BYTES);      // bf16, 12.8 MB
    int*   EP   = (int*)  (ws + 2 * BF_BYTES);                 // NE ints (6.4 MB)
    int*   H    = EP   + NE;                                   // NS ints
    int*   bsum = H    + NS;                                   // NSB+1
    int*   deg  = bsum + NSB + 1;                              // NN
    float* M    = (float*)(deg + NN);                          // 128*40
    float* cfc  = M + 128 * NCLS;                              // 40

    const int* src = EI;          // edge_index[0,:]
    const int* dst = EI + NE;     // edge_index[1,:]

    // ---- bucket edges by src>>6 ----
    bucket_hist<<<NHB, 256, 0, stream>>>(src, H);
    scan_local<<<NSB, SCAN_B, 0, stream>>>(H, bsum);
    scan_bsums<<<1, 1024, 0, stream>>>(bsum);
    scan_add<<<NSB, SCAN_B, 0, stream>>>(H, bsum);
    bucket_scatter<<<NHB, 256, 0, stream>>>(src, dst, H, EP);

    // ---- tail-weight precompute ----
    small_prep<<<(128 * NCLS + 255) / 256, 256, 0, stream>>>(W2, Wfc, b2, M, cfc);

    // ---- H1 = relu(F @ W1 + b1) -> A (bf16, MFMA) ----
    gemm1_mfma<<<(NN + 63) / 64, 256, 0, stream>>>(F, W1, b1, A);

    // ---- S1 = gather-sum(A) -> B (+deg) ----
    bucket_gather<true><<<NBUK, 512, 0, stream>>>(H, EP, A, B, deg);

    // ---- T = gather-sum(B) -> A ----
    bucket_gather<false><<<NBUK, 512, 0, stream>>>(H, EP, B, A, nullptr);

    // ---- out = T @ M + deg*cfc + bfc ----
    fc_tail<<<(NN * NCLS + 255) / 256, 256, 0, stream>>>(A, M, cfc, bfc, deg, out);
}